// Round 3
// baseline (219.647 us; speedup 1.0000x reference)
//
#include <hip/hip_runtime.h>
#include <cstdint>

// (8, 4096, 6) fp32 both inputs; scalar fp32 output.
#define NB 8
#define NP 4096
#define NDB 16                    // 2 directions * 8 batches
#define THREADS 256
#define Q 8                       // query points per thread (registers)
#define CHUNK (THREADS * Q)       // 2048 queries per block
#define NCHUNK (NP / CHUNK)       // 2
#define SEG 32                    // target split across blocks
#define TSEG (NP / SEG)           // 128 targets per LDS tile
#define BPD (NCHUNK * SEG)        // 64 blocks per (dir,b)

// Single fused kernel. Phase 1 (all 1024 blocks): segmented argmin via
// s = q·t - 0.5|t|^2 (3 FMA; bias precomputed into LDS float4.w), best
// tracked with cmp+cndmask+max (3 inst) -> 6 VALU inst/pair. Epilogue
// computes the normal-distance for the block's partial winner (32x redundant
// but ~2us device-wide) and stores (packed_key, nd) per (seg,query):
// key = float_bits(d) chopped to 20 bits | 12-bit target idx (d>=0 so uint
// order == float order; ties -> lowest idx = argmin first-occurrence).
// Phase 2: last-done block per (dir,b) min-reduces the 32 partials per query
// (no gathers needed -- nd already attached), block-reduces, and the last
// db-finisher sums all 16 db partial sums and writes d_out directly.

__global__ __launch_bounds__(THREADS) void chamfer_fused(
    const float* __restrict__ xyz1, const float* __restrict__ xyz2,
    unsigned int* __restrict__ ws, float* __restrict__ out)
{
    unsigned int* cnt   = ws;                     // [NDB], zeroed by memset
    unsigned int* gcnt  = ws + 16;                // zeroed by memset
    float*        dbsum = (float*)(ws + 32);      // [NDB], fully overwritten
    unsigned int* keys  = ws + 1024;              // [NDB][SEG][NP]
    float*        nds   = (float*)(ws + 1024 + NDB * SEG * NP);

    __shared__ float4 tgt[TSEG];

    unsigned int x = blockIdx.x;                  // ((db*NCHUNK+chunk)*SEG+seg)
    int seg   = x & (SEG - 1);
    int chunk = (x >> 5) & (NCHUNK - 1);
    int db    = x >> 6;
    int b     = db & 7;
    int dir   = db >> 3;

    const float* qset = dir ? xyz2 : xyz1;
    const float* tset = dir ? xyz1 : xyz2;

    // Stage this segment's targets into LDS with -0.5|t|^2 bias in .w.
    int tbase = seg * TSEG;
    if (threadIdx.x < TSEG) {
        const float* src = tset + ((size_t)b * NP + tbase + threadIdx.x) * 6;
        float tx = src[0], ty = src[1], tz = src[2];
        tgt[threadIdx.x] =
            make_float4(tx, ty, tz, -0.5f * (tx * tx + ty * ty + tz * tz));
    }
    __syncthreads();

    // Q query points in registers (stride THREADS between qi).
    float qx[Q], qy[Q], qz[Q], qq[Q], bs[Q];
    unsigned int bi[Q];
    int qbase = chunk * CHUNK + threadIdx.x;
    #pragma unroll
    for (int i = 0; i < Q; ++i) {
        const float* src = qset + ((size_t)b * NP + qbase + i * THREADS) * 6;
        qx[i] = src[0]; qy[i] = src[1]; qz[i] = src[2];
        qq[i] = qx[i] * qx[i] + qy[i] * qy[i] + qz[i] * qz[i];
        bs[i] = -3.4e38f;
        bi[i] = 0u;
    }

    // Inner scan: wave-uniform LDS broadcast read amortized over Q=8.
    #pragma unroll 4
    for (int k = 0; k < TSEG; ++k) {
        float4 t = tgt[k];
        unsigned int jb = (unsigned int)(tbase + k);
        #pragma unroll
        for (int i = 0; i < Q; ++i) {
            float s = fmaf(t.x, qx[i], fmaf(t.y, qy[i], fmaf(t.z, qz[i], t.w)));
            bi[i] = (s > bs[i]) ? jb : bi[i];     // v_cmp + v_cndmask
            bs[i] = fmaxf(bs[i], s);              // v_max
        }
    }

    // Epilogue: packed key + normal-distance for the partial winner.
    size_t srow = ((size_t)db * SEG + seg) * NP;
    #pragma unroll
    for (int i = 0; i < Q; ++i) {
        int q = qbase + i * THREADS;
        int j = (int)bi[i];
        float d = fmaxf(fmaf(-2.0f, bs[i], qq[i]), 0.0f);
        unsigned int key = (__float_as_uint(d) & 0xFFFFF000u) | (unsigned int)j;

        const float* nq = qset + ((size_t)b * NP + q) * 6 + 3;
        const float* nt = tset + ((size_t)b * NP + j) * 6 + 3;
        float ax = nq[0], ay = nq[1], az = nq[2];
        float bx = nt[0], by = nt[1], bz = nt[2];
        float na = fmaxf(sqrtf(ax * ax + ay * ay + az * az), 1e-12f);
        float nbv = fmaxf(sqrtf(bx * bx + by * by + bz * bz), 1e-12f);
        float ra = 1.0f / na, rb = 1.0f / nbv;
        float dx = ax * ra - bx * rb;
        float dy = ay * ra - by * rb;
        float dz = az * ra - bz * rb;
        float nd = dx * dx + dy * dy + dz * dz;

        keys[srow + q] = key;
        nds[srow + q]  = nd;
    }

    // Release our stores, then count this block done for its db.
    __threadfence();
    __syncthreads();
    __shared__ unsigned int done;
    if (threadIdx.x == 0) done = atomicAdd(&cnt[db], 1u);
    __syncthreads();
    if (done != BPD - 1) return;

    // ---- db finisher (block-uniform path) ----
    __threadfence();                              // acquire others' stores
    const unsigned int* kb = keys + (size_t)db * SEG * NP;
    const float*        nb = nds + (size_t)db * SEG * NP;
    float acc = 0.0f;
    for (int q = threadIdx.x; q < NP; q += THREADS) {   // 16 iters, coalesced
        unsigned int p = kb[q];
        int wseg = 0;
        #pragma unroll
        for (int s2 = 1; s2 < SEG; ++s2) {
            unsigned int v = kb[(size_t)s2 * NP + q];
            if (v < p) { p = v; wseg = s2; }
        }
        float dist = __uint_as_float(p & 0xFFFFF000u);
        acc += dist + nb[(size_t)wseg * NP + q];
    }
    for (int off = 32; off > 0; off >>= 1)
        acc += __shfl_down(acc, off, 64);
    __shared__ float wsum[4];
    if ((threadIdx.x & 63) == 0) wsum[threadIdx.x >> 6] = acc;
    __syncthreads();
    if (threadIdx.x != 0) return;

    dbsum[db] = (wsum[0] + wsum[1] + wsum[2] + wsum[3]) * (1.0f / 32768.0f);
    __threadfence();
    unsigned int o2 = atomicAdd(gcnt, 1u);
    if (o2 == NDB - 1) {                          // global finisher
        __threadfence();
        float t = 0.0f;
        #pragma unroll
        for (int k2 = 0; k2 < NDB; ++k2) t += dbsum[k2];
        *out = t;
    }
}

extern "C" void kernel_launch(void* const* d_in, const int* in_sizes, int n_in,
                              void* d_out, int out_size, void* d_ws, size_t ws_size,
                              hipStream_t stream) {
    const float* xyz1 = (const float*)d_in[0];
    const float* xyz2 = (const float*)d_in[1];

    // Zero the 16 per-db counters + 1 global counter (68 bytes).
    hipMemsetAsync(d_ws, 0, 68, stream);

    chamfer_fused<<<NDB * BPD, THREADS, 0, stream>>>(
        xyz1, xyz2, (unsigned int*)d_ws, (float*)d_out);
}

// Round 4
// 110.706 us; speedup vs baseline: 1.9841x; 1.9841x over previous
//
#include <hip/hip_runtime.h>
#include <cstdint>

// (8, 4096, 6) fp32 inputs; scalar fp32 output.
#define NB 8
#define NP 4096
#define NDB 16                     // 2 dirs * 8 batches
#define THREADS 256
#define Q 4                        // queries per thread
#define CHUNK (THREADS * Q)        // 1024
#define NCHUNK (NP / CHUNK)        // 4
#define SEG 32                     // target split
#define TSEG (NP / SEG)            // 128
#define BIAS 80.0f                 // makes score s' = q.t + (80-0.5|t|^2) > 0 always

// ws layout (bytes):
//   pk   : float4[16][4096]  @ 0        (x,y,z, 80-0.5|p|^2)      1 MB
//   nrm  : float4[16][4096]  @ 1 MB     (normalized normal)        1 MB
//   keys : u32 [16][32][4096]@ 2 MB     (d chopped 20b | 12b j)    8 MB
//   vals : f32 [16][32][4096]@ 10 MB    (d + nd of seg winner)     8 MB

__global__ __launch_bounds__(256) void chamfer_prep(
    const float* __restrict__ xyz1, const float* __restrict__ xyz2,
    float4* __restrict__ pk, float4* __restrict__ nrm)
{
    int gid = blockIdx.x * 256 + threadIdx.x;    // 0..65535 = [c][b][p]
    int c = gid >> 15;
    const float* src = (c ? xyz2 : xyz1) + (size_t)(gid & 32767) * 6;
    const float2* s2 = (const float2*)src;       // byte offset 24p: 8-aligned
    float2 a = s2[0], bv = s2[1], cv = s2[2];    // (x,y) (z,nx) (ny,nz)
    float x = a.x, y = a.y, z = bv.x;
    float nx = bv.y, ny = cv.x, nz = cv.y;
    pk[gid] = make_float4(x, y, z, BIAS - 0.5f * (x * x + y * y + z * z));
    float rn = 1.0f / fmaxf(sqrtf(nx * nx + ny * ny + nz * nz), 1e-12f);
    nrm[gid] = make_float4(nx * rn, ny * rn, nz * rn, 0.0f);
}

// Inner pair: s' = fma(tx,qx,fma(ty,qy,fma(tz,qz,tw)))  (3 FMA, bias folded)
//             key = (bits(s') & ~0x7F) | (127-k)        (v_and_or_b32)
//             bk  = max(bk, key)                        (v_max_u32)
// s' > 0 so uint order == float order; max key -> max s' -> min d; tie ->
// max (127-k) -> min k -> argmin first-occurrence. 7-bit chop: d err <= 2^-8.
__global__ __launch_bounds__(THREADS) void chamfer_argmin(
    const float4* __restrict__ pk, const float4* __restrict__ nrm,
    unsigned int* __restrict__ keys, float* __restrict__ vals)
{
    unsigned int x = blockIdx.x;             // ((db*NCHUNK+chunk)*SEG+seg)
    int seg   = x & (SEG - 1);
    int chunk = (x >> 5) & (NCHUNK - 1);
    int db    = x >> 7;
    int b     = db & 7;
    int dir   = db >> 3;
    int qrow  = dir * NB + b;                // query cloud row in pk/nrm
    int trow  = (1 - dir) * NB + b;          // target cloud row

    int tbase = seg * TSEG;
    const float4* tp = pk + (size_t)trow * NP + tbase;   // wave-uniform reads
    const float4* qp = pk + (size_t)qrow * NP;

    float qx[Q], qy[Q], qz[Q], qw[Q];
    unsigned int bk[Q];
    int qbase = chunk * CHUNK + threadIdx.x;
    #pragma unroll
    for (int i = 0; i < Q; ++i) {
        float4 qv = qp[qbase + i * THREADS];             // coalesced b128
        qx[i] = qv.x; qy[i] = qv.y; qz[i] = qv.z; qw[i] = qv.w;
        bk[i] = 0u;
    }

    #pragma unroll 8
    for (int k = 0; k < TSEG; ++k) {
        float4 t = tp[k];                    // uniform addr -> s_load (SMEM)
        unsigned int kc = (unsigned int)(TSEG - 1 - k);
        #pragma unroll
        for (int i = 0; i < Q; ++i) {
            float s = fmaf(t.x, qx[i], fmaf(t.y, qy[i], fmaf(t.z, qz[i], t.w)));
            unsigned int key = (__float_as_uint(s) & 0xFFFFFF80u) | kc;
            bk[i] = bk[i] > key ? bk[i] : key;
        }
    }

    // Epilogue: d = |q|^2 + 2*BIAS - 2 s'  with |q|^2 = 2*BIAS - 2 qw
    //           -> d = 4*BIAS - 2 qw - 2 s'chop
    size_t srow = ((size_t)db * SEG + seg) * NP;
    const float4* nq = nrm + (size_t)qrow * NP;
    const float4* nt = nrm + (size_t)trow * NP;
    #pragma unroll
    for (int i = 0; i < Q; ++i) {
        int q = qbase + i * THREADS;
        unsigned int u = bk[i];
        float sc = __uint_as_float(u & 0xFFFFFF80u);
        int j = tbase + (TSEG - 1) - (int)(u & 0x7Fu);
        float d = fmaxf(4.0f * BIAS - 2.0f * qw[i] - 2.0f * sc, 0.0f);
        unsigned int key = (__float_as_uint(d) & 0xFFFFF000u) | (unsigned int)j;

        float4 a = nq[q];                    // coalesced
        float4 t = nt[j];                    // scattered 16B, L2-resident
        float dot = a.x * t.x + a.y * t.y + a.z * t.z;
        float nd = fmaf(-2.0f, dot, 2.0f);   // |n1-n2|^2 for unit vectors

        keys[srow + q] = key;
        vals[srow + q] = d + nd;
    }
}

__global__ __launch_bounds__(128) void chamfer_finish(
    const unsigned int* __restrict__ keys, const float* __restrict__ vals,
    float* __restrict__ out)
{
    int gid = blockIdx.x * 128 + threadIdx.x;    // 0..65535 = db*NP+q
    int q  = gid & (NP - 1);
    int db = gid >> 12;

    const unsigned int* kb = keys + (size_t)db * SEG * NP + q;
    unsigned int p = kb[0];
    int wseg = 0;
    #pragma unroll
    for (int s = 1; s < SEG; ++s) {
        unsigned int v = kb[(size_t)s * NP];
        if (v < p) { p = v; wseg = s; }
    }
    float contrib = vals[((size_t)db * SEG + wseg) * NP + q] * (1.0f / 32768.0f);

    for (int off = 32; off > 0; off >>= 1)
        contrib += __shfl_down(contrib, off, 64);
    __shared__ float wsum[2];
    if ((threadIdx.x & 63) == 0) wsum[threadIdx.x >> 6] = contrib;
    __syncthreads();
    if (threadIdx.x == 0) atomicAdd(out, wsum[0] + wsum[1]);
}

extern "C" void kernel_launch(void* const* d_in, const int* in_sizes, int n_in,
                              void* d_out, int out_size, void* d_ws, size_t ws_size,
                              hipStream_t stream) {
    const float* xyz1 = (const float*)d_in[0];
    const float* xyz2 = (const float*)d_in[1];
    char* ws = (char*)d_ws;
    float4* pk        = (float4*)(ws);
    float4* nrm       = (float4*)(ws + (1u << 20));
    unsigned int* keys = (unsigned int*)(ws + (2u << 20));
    float* vals        = (float*)(ws + (10u << 20));

    hipMemsetAsync(d_out, 0, sizeof(float), stream);
    chamfer_prep<<<256, 256, 0, stream>>>(xyz1, xyz2, pk, nrm);
    chamfer_argmin<<<NDB * NCHUNK * SEG, THREADS, 0, stream>>>(pk, nrm, keys, vals);
    chamfer_finish<<<(NDB * NP) / 128, 128, 0, stream>>>(keys, vals, (float*)d_out);
}

// Round 5
// 96.938 us; speedup vs baseline: 2.2659x; 1.1420x over previous
//
#include <hip/hip_runtime.h>
#include <cstdint>

// (8, 4096, 6) fp32 inputs; scalar fp32 output.
#define NB 8
#define NP 4096
#define NDB 16                     // 2 dirs * 8 batches
#define THREADS 256
#define Q 8                        // queries per thread
#define CHUNK (THREADS * Q)        // 2048
#define NCHUNK (NP / CHUNK)        // 2
#define SEG 64                     // target split
#define TSEG (NP / SEG)            // 64 targets per block

// ws layout (bytes):
//   pk     : float4[16][4096] @ 0      (x,y,z, -0.5|p|^2)          1 MB
//   nrm    : float4[16][4096] @ 1 MB   (unit normal)                1 MB
//   scores : f32 [16][64][4096] @ 2 MB (per-seg max score)         16 MB
//
// Hot loop carries NO index: score s' = q.t - 0.5|t|^2, 3 v_fma + 1 v_max
// = 4 VALU inst/pair, all-VGPR operands (targets broadcast from LDS).
// max s' == min d (d = |q|^2 - 2 s'). The argmin index is recovered in
// finish by re-running the identical fmaf chain over the winning segment's
// 64 targets and taking the first bit-exact score match (IEEE-deterministic;
// first hit = lowest j = reference argmin tie semantics).

__global__ __launch_bounds__(256) void chamfer_prep(
    const float* __restrict__ xyz1, const float* __restrict__ xyz2,
    float4* __restrict__ pk, float4* __restrict__ nrm)
{
    int gid = blockIdx.x * 256 + threadIdx.x;    // 0..65535 = [c][b][p]
    int c = gid >> 15;
    const float* src = (c ? xyz2 : xyz1) + (size_t)(gid & 32767) * 6;
    const float2* s2 = (const float2*)src;       // 24B stride: 8-aligned
    float2 a = s2[0], bv = s2[1], cv = s2[2];    // (x,y) (z,nx) (ny,nz)
    float x = a.x, y = a.y, z = bv.x;
    float nx = bv.y, ny = cv.x, nz = cv.y;
    pk[gid] = make_float4(x, y, z, -0.5f * (x * x + y * y + z * z));
    float rn = 1.0f / fmaxf(sqrtf(nx * nx + ny * ny + nz * nz), 1e-12f);
    nrm[gid] = make_float4(nx * rn, ny * rn, nz * rn, 0.0f);
}

__global__ __launch_bounds__(THREADS) void chamfer_argmin(
    const float4* __restrict__ pk, float* __restrict__ scores)
{
    __shared__ float4 tgt[TSEG];

    unsigned int x = blockIdx.x;             // ((db*NCHUNK+chunk)*SEG+seg)
    int seg   = x & (SEG - 1);
    int chunk = (x >> 6) & (NCHUNK - 1);
    int db    = x >> 7;
    int b     = db & 7;
    int dir   = db >> 3;
    int qrow  = dir * NB + b;
    int trow  = (1 - dir) * NB + b;

    if (threadIdx.x < TSEG)
        tgt[threadIdx.x] = pk[(size_t)trow * NP + seg * TSEG + threadIdx.x];
    __syncthreads();

    const float4* qp = pk + (size_t)qrow * NP;
    float qx[Q], qy[Q], qz[Q], bs[Q];
    int qbase = chunk * CHUNK + threadIdx.x;
    #pragma unroll
    for (int i = 0; i < Q; ++i) {
        float4 qv = qp[qbase + i * THREADS];     // coalesced b128
        qx[i] = qv.x; qy[i] = qv.y; qz[i] = qv.z;
        bs[i] = -3.4e38f;
    }

    // 4 VALU inst/pair: 3 fma + 1 max. LDS read broadcast, amortized over Q=8.
    #pragma unroll 8
    for (int k = 0; k < TSEG; ++k) {
        float4 t = tgt[k];
        #pragma unroll
        for (int i = 0; i < Q; ++i) {
            float s = fmaf(t.x, qx[i], fmaf(t.y, qy[i], fmaf(t.z, qz[i], t.w)));
            bs[i] = fmaxf(bs[i], s);
        }
    }

    float* srow = scores + ((size_t)db * SEG + seg) * NP + qbase;
    #pragma unroll
    for (int i = 0; i < Q; ++i) srow[i * THREADS] = bs[i];
}

__global__ __launch_bounds__(256) void chamfer_finish(
    const float4* __restrict__ pk, const float4* __restrict__ nrm,
    const float* __restrict__ scores, float* __restrict__ out)
{
    int gid = blockIdx.x * 256 + threadIdx.x;    // 0..65535 = db*NP+q
    int q  = gid & (NP - 1);
    int db = gid >> 12;
    int b  = db & 7;
    int dir = db >> 3;
    int qrow = dir * NB + b;
    int trow = (1 - dir) * NB + b;

    // Winning segment: first strict max over 64 per-seg scores (coalesced).
    const float* sb = scores + (size_t)db * SEG * NP + q;
    float best = -3.4e38f;
    int wseg = 0;
    #pragma unroll
    for (int s = 0; s < SEG; ++s) {
        float v = sb[(size_t)s * NP];
        wseg = (v > best) ? s : wseg;
        best = fmaxf(best, v);
    }

    // Recover argmin index: identical fmaf chain, first bit-exact match.
    float4 qv = pk[(size_t)qrow * NP + q];
    const float4* tb = pk + (size_t)trow * NP + wseg * TSEG;
    int jf = -1;
    #pragma unroll 8
    for (int k = 0; k < TSEG; ++k) {
        float4 t = tb[k];
        float s = fmaf(t.x, qv.x, fmaf(t.y, qv.y, fmaf(t.z, qv.z, t.w)));
        bool hit = (s == best) && (jf < 0);
        jf = hit ? k : jf;
    }
    int j = wseg * TSEG + (jf < 0 ? 0 : jf);

    // d = |q|^2 - 2 s' ;  |q|^2 = -2 qv.w  ->  d = -2 (qv.w + best)
    float d = fmaxf(-2.0f * (qv.w + best), 0.0f);

    float4 a = nrm[(size_t)qrow * NP + q];
    float4 t = nrm[(size_t)trow * NP + j];
    float dot = a.x * t.x + a.y * t.y + a.z * t.z;
    float nd = fmaf(-2.0f, dot, 2.0f);           // |n1-n2|^2, unit vectors

    float contrib = (d + nd) * (1.0f / 32768.0f);
    for (int off = 32; off > 0; off >>= 1)
        contrib += __shfl_down(contrib, off, 64);
    __shared__ float wsum[4];
    if ((threadIdx.x & 63) == 0) wsum[threadIdx.x >> 6] = contrib;
    __syncthreads();
    if (threadIdx.x == 0)
        atomicAdd(out, wsum[0] + wsum[1] + wsum[2] + wsum[3]);
}

extern "C" void kernel_launch(void* const* d_in, const int* in_sizes, int n_in,
                              void* d_out, int out_size, void* d_ws, size_t ws_size,
                              hipStream_t stream) {
    const float* xyz1 = (const float*)d_in[0];
    const float* xyz2 = (const float*)d_in[1];
    char* ws = (char*)d_ws;
    float4* pk     = (float4*)(ws);
    float4* nrm    = (float4*)(ws + (1u << 20));
    float*  scores = (float*)(ws + (2u << 20));

    hipMemsetAsync(d_out, 0, sizeof(float), stream);
    chamfer_prep<<<256, 256, 0, stream>>>(xyz1, xyz2, pk, nrm);
    chamfer_argmin<<<NDB * NCHUNK * SEG, THREADS, 0, stream>>>(pk, scores);
    chamfer_finish<<<(NDB * NP) / 256, 256, 0, stream>>>(pk, nrm, scores, (float*)d_out);
}